// Round 12
// baseline (41.164 us; speedup 1.0000x reference)
//
#include <hip/hip_runtime.h>
#include <hip/hip_bf16.h>

typedef __attribute__((ext_vector_type(8))) short bf16x8;
typedef __attribute__((ext_vector_type(4))) float f32x4;
typedef __attribute__((ext_vector_type(4))) unsigned short us4;

#define BATCH 8
#define SEQ 2048
#define DIM 64
#define QB 64                  // q rows per block (4 waves x 16)
#define NQT 32
#define NKT 32
#define TE 4096                // elems per 64x64 tile
#define CH 2                   // kv tiles per chunk
#define CPB 272                // chunks per batch = sum ceil((qi+1)/2)
#define QSCALE (0.125f * 1.44269504088896f)  // 1/sqrt(64) * log2(e)
#define THR 8.0f

__device__ __forceinline__ unsigned short f2bf(float f) {
    return __builtin_bit_cast(unsigned short, __float2bfloat16(f));
}
__device__ __forceinline__ float bf2f(unsigned short u) {
    return __builtin_bit_cast(float, (unsigned)u << 16);
}

__device__ __forceinline__ int kswz(int row, int d) {
    return (row * DIM + d) ^ ((row & 7) << 3);
}
__device__ __forceinline__ int vswz(int d, int kv) {
    return (d * 64 + kv) ^ ((((d & 7) ^ ((d >> 2) & 7)) & 7) << 3);
}
__device__ __forceinline__ int pswz(int row, int kv) {
    return (row * 64 + kv) ^ ((row & 7) << 3);
}

#define GLOAD16(gsrc, ldst)                                                     \
    __builtin_amdgcn_global_load_lds(                                           \
        (const __attribute__((address_space(1))) void*)(gsrc),                  \
        (__attribute__((address_space(3))) void*)(ldst), 16, 0, 0)

// ---- pre-pass: fp32 K,V -> bf16 swizzled tiles; blockIdx&7 = batch ----
__global__ __launch_bounds__(256) void prep_kernel(const float* __restrict__ K,
                                                   const float* __restrict__ V,
                                                   unsigned short* __restrict__ Kp,
                                                   unsigned short* __restrict__ Vp) {
    const int batch = blockIdx.x & 7;
    const int t = blockIdx.x >> 3;
    const int tile = batch * NKT + t;
    const int tid = threadIdx.x;
    const float* Kt = K + (size_t)tile * TE;
    const float* Vt = V + (size_t)tile * TE;
    unsigned short* Kd = Kp + (size_t)tile * TE;
    unsigned short* Vd = Vp + (size_t)tile * TE;
    #pragma unroll
    for (int i = 0; i < 4; ++i) {
        int idx = i * 256 + tid;
        int row = idx >> 4;
        int d0 = (idx & 15) << 2;
        f32x4 kf = *(const f32x4*)(Kt + row * DIM + d0);
        us4 kb = {f2bf(kf[0]), f2bf(kf[1]), f2bf(kf[2]), f2bf(kf[3])};
        *(us4*)(&Kd[kswz(row, d0)]) = kb;
    }
    const int dt4 = tid & 15, k4 = tid >> 4;
    f32x4 vf[4];
    #pragma unroll
    for (int rr = 0; rr < 4; ++rr)
        vf[rr] = *(const f32x4*)(Vt + (k4 * 4 + rr) * DIM + dt4 * 4);
    #pragma unroll
    for (int dd = 0; dd < 4; ++dd) {
        us4 vb = {f2bf(vf[0][dd]), f2bf(vf[1][dd]), f2bf(vf[2][dd]), f2bf(vf[3][dd])};
        *(us4*)(&Vd[vswz(dt4 * 4 + dd, k4 * 4)]) = vb;
    }
}

// ---- main flash kernel: block = (batch, q-tile, chunk of <=2 kv-tiles) ----
__global__ __launch_bounds__(256, 4) void fa_kernel(const float* __restrict__ Q,
                                                    const unsigned short* __restrict__ Kp,
                                                    const unsigned short* __restrict__ Vp,
                                                    unsigned short* __restrict__ PO,
                                                    float* __restrict__ PM,
                                                    float* __restrict__ PL,
                                                    float* __restrict__ O) {
    __shared__ unsigned short KL[2][4096];   // 16 KB
    __shared__ unsigned short VL[2][4096];   // 16 KB
    __shared__ unsigned short PB[4][1024];   // 8 KB  -> total 40960 B exactly

    const int tid = threadIdx.x;
    const int w = tid >> 6, lane = tid & 63, g = lane >> 4, c = lane & 15;

    // decode: chunk c0 within batch; big chunks (high qi) first.
    // pair structure: a = qi>>1; pfx(2a)=a(a+1), pfx(2a+1)=(a+1)^2; nc=a+1
    const int slot = blockIdx.x;
    const int batch = slot & 7;
    const int c0 = (CPB - 1) - (slot >> 3);          // 0..271
    int a = 0;
    #pragma unroll
    for (int gg = 1; gg < 16; ++gg) a = (c0 >= gg * (gg + 1)) ? gg : a;
    const int nc = a + 1;
    const int x = c0 - a * (a + 1);
    int qi, sp;
    if (x < nc) { qi = 2 * a; sp = x; }
    else        { qi = 2 * a + 1; sp = x - nc; }

    const int q0 = qi * QB;
    const int nt = qi + 1;
    const int t0 = sp * CH;
    const int t1 = (t0 + CH < nt) ? (t0 + CH) : nt;
    const int tiles = t1 - t0;
    const bool dchunk = (t1 == nt);

    const unsigned short* Kb = Kp + (size_t)batch * NKT * TE;
    const unsigned short* Vb = Vp + (size_t)batch * NKT * TE;

#define STAGE_TILE(tidx, buf)                                          \
    do {                                                               \
        const char* Ks_ = (const char*)(Kb + (size_t)(tidx) * TE);     \
        const char* Vs_ = (const char*)(Vb + (size_t)(tidx) * TE);     \
        char* kd_ = (char*)&KL[buf][0];                                \
        char* vd_ = (char*)&VL[buf][0];                                \
        _Pragma("unroll")                                              \
        for (int i_ = 0; i_ < 2; ++i_) {                               \
            int off_ = (w * 2 + i_) * 1024;                            \
            GLOAD16(Ks_ + off_ + lane * 16, kd_ + off_);               \
            GLOAD16(Vs_ + off_ + lane * 16, vd_ + off_);               \
        }                                                              \
    } while (0)

    STAGE_TILE(t0, 0);

    // Q fragments (overlap with staging)
    const float* Qrow = Q + (size_t)(batch * SEQ + q0 + w * 16 + c) * DIM;
    f32x4 qf0 = *(const f32x4*)(Qrow + g * 8);
    f32x4 qf1 = *(const f32x4*)(Qrow + g * 8 + 4);
    f32x4 qf2 = *(const f32x4*)(Qrow + 32 + g * 8);
    f32x4 qf3 = *(const f32x4*)(Qrow + 32 + g * 8 + 4);
    bf16x8 qa[2];
    #pragma unroll
    for (int j = 0; j < 4; ++j) {
        qa[0][j]     = (short)f2bf(qf0[j] * QSCALE);
        qa[0][j + 4] = (short)f2bf(qf1[j] * QSCALE);
        qa[1][j]     = (short)f2bf(qf2[j] * QSCALE);
        qa[1][j + 4] = (short)f2bf(qf3[j] * QSCALE);
    }

    float m[4], lsum[4];
    f32x4 o[4];
    #pragma unroll
    for (int r = 0; r < 4; ++r) { m[r] = -1e30f; lsum[r] = 0.f; }
    #pragma unroll
    for (int dt = 0; dt < 4; ++dt) o[dt] = f32x4{0.f, 0.f, 0.f, 0.f};

    __builtin_amdgcn_sched_barrier(0);
    asm volatile("s_waitcnt vmcnt(0)" ::: "memory");
    __builtin_amdgcn_s_barrier();
    __builtin_amdgcn_sched_barrier(0);

    for (int u = 0; u < tiles; ++u) {
        const int cb = u & 1;
        const bool last = (u == tiles - 1);

        if (!last) STAGE_TILE(t0 + u + 1, cb ^ 1);

        // ---- QK^T ----
        f32x4 s[4];
        #pragma unroll
        for (int n = 0; n < 4; ++n) s[n] = f32x4{0.f, 0.f, 0.f, 0.f};
        __builtin_amdgcn_s_setprio(1);
        #pragma unroll
        for (int n = 0; n < 4; ++n)
            #pragma unroll
            for (int f = 0; f < 2; ++f) {
                bf16x8 kb = *(bf16x8*)(&KL[cb][kswz(n * 16 + c, f * 32 + g * 8)]);
                s[n] = __builtin_amdgcn_mfma_f32_16x16x32_bf16(qa[f], kb, s[n], 0, 0, 0);
            }
        __builtin_amdgcn_s_setprio(0);

        if (dchunk && last) {
            const int dbase = (nt - 1) * 64;
            #pragma unroll
            for (int n = 0; n < 4; ++n) {
                int col = dbase + n * 16 + c;
                #pragma unroll
                for (int r = 0; r < 4; ++r)
                    if (col > q0 + w * 16 + g * 4 + r) s[n][r] = -1e30f;
            }
        }

        // ---- softmax: local-max THR check (no cross-lane in common path) ----
        float pmx[4];
        #pragma unroll
        for (int r = 0; r < 4; ++r)
            pmx[r] = fmaxf(fmaxf(s[0][r], s[1][r]), fmaxf(s[2][r], s[3][r]));
        bool need = false;
        #pragma unroll
        for (int r = 0; r < 4; ++r) need |= (pmx[r] > m[r] + THR);
        if (__any(need)) {
            #pragma unroll
            for (int r = 0; r < 4; ++r) {
                float t2 = pmx[r];
                t2 = fmaxf(t2, __shfl_xor(t2, 1));
                t2 = fmaxf(t2, __shfl_xor(t2, 2));
                t2 = fmaxf(t2, __shfl_xor(t2, 4));
                t2 = fmaxf(t2, __shfl_xor(t2, 8));
                float mn = fmaxf(m[r], t2);
                float alpha = exp2f(m[r] - mn);
                m[r] = mn;
                lsum[r] *= alpha;
                #pragma unroll
                for (int dt = 0; dt < 4; ++dt) o[dt][r] *= alpha;
            }
        }
        #pragma unroll
        for (int n = 0; n < 4; ++n)
            #pragma unroll
            for (int r = 0; r < 4; ++r) {
                float pe = exp2f(s[n][r] - m[r]);
                s[n][r] = pe;
                lsum[r] += pe;          // per-lane partial; reduced in epilogue
            }

        // ---- P -> own wave LDS region (wave-local hazard, no barrier) ----
        unsigned short* Pw = &PB[w][0];
        #pragma unroll
        for (int n = 0; n < 4; ++n)
            #pragma unroll
            for (int r = 0; r < 4; ++r)
                Pw[pswz(g * 4 + r, n * 16 + c)] = f2bf(s[n][r]);
        asm volatile("s_waitcnt lgkmcnt(0)" ::: "memory");
        __builtin_amdgcn_sched_barrier(0);

        // ---- PV ----
        __builtin_amdgcn_s_setprio(1);
        #pragma unroll
        for (int ks = 0; ks < 2; ++ks) {
            bf16x8 pa = *(bf16x8*)(&Pw[pswz(c, ks * 32 + g * 8)]);
            #pragma unroll
            for (int dt = 0; dt < 4; ++dt) {
                bf16x8 vb = *(bf16x8*)(&VL[cb][vswz(dt * 16 + c, ks * 32 + g * 8)]);
                o[dt] = __builtin_amdgcn_mfma_f32_16x16x32_bf16(pa, vb, o[dt], 0, 0, 0);
            }
        }
        __builtin_amdgcn_s_setprio(0);

        if (!last) {
            __builtin_amdgcn_sched_barrier(0);
            asm volatile("s_waitcnt vmcnt(0)" ::: "memory");
            __builtin_amdgcn_s_barrier();
            __builtin_amdgcn_sched_barrier(0);
        }
    }

    // ---- reduce per-lane l partials across the 16-lane group ----
    float l[4];
    #pragma unroll
    for (int r = 0; r < 4; ++r) {
        float ts = lsum[r];
        ts += __shfl_xor(ts, 1);
        ts += __shfl_xor(ts, 2);
        ts += __shfl_xor(ts, 4);
        ts += __shfl_xor(ts, 8);
        l[r] = ts;
    }

    // ---- epilogue ----
    if (nc == 1) {           // qi 0,1: single chunk, direct O write
        #pragma unroll
        for (int r = 0; r < 4; ++r) {
            float inv = 1.f / l[r];
            float* Orow = O + (size_t)(batch * SEQ + q0 + w * 16 + g * 4 + r) * DIM;
            #pragma unroll
            for (int dt = 0; dt < 4; ++dt)
                Orow[dt * 16 + c] = o[dt][r] * inv;
        }
    } else {
        unsigned short* Pbase = PO + (size_t)slot * (QB * DIM);
        #pragma unroll
        for (int r = 0; r < 4; ++r) {
            int rowin = w * 16 + g * 4 + r;
            #pragma unroll
            for (int dt = 0; dt < 4; ++dt)
                Pbase[rowin * DIM + dt * 16 + c] = f2bf(o[dt][r]);
            if (c == 0) {
                PM[(size_t)slot * QB + rowin] = m[r];
                PL[(size_t)slot * QB + rowin] = l[r];
            }
        }
    }
#undef STAGE_TILE
}

// ---- combine (q-tiles with qi>=2), single-pass online, bf16 partials ----
__global__ __launch_bounds__(256) void combine_kernel(const unsigned short* __restrict__ PO,
                                                      const float* __restrict__ PM,
                                                      const float* __restrict__ PL,
                                                      float* __restrict__ O) {
    const int tid = threadIdx.x;
    const int ridx = blockIdx.x * 16 + (tid >> 4);
    const int d0 = (tid & 15) << 2;
    const int batch = ridx / 1920;          // 30 q-tiles x 64 rows per batch
    const int rem = ridx - batch * 1920;
    const int qi = 2 + (rem >> 6);
    const int rowin = rem & 63;
    const int a = qi >> 1, b = qi & 1;
    const int nc = a + 1;
    const int pfx = (a + b) * (a + 1);

    float mrun = -1e30f, ls = 0.f;
    f32x4 os = {0.f, 0.f, 0.f, 0.f};
    for (int sp = 0; sp < nc; ++sp) {
        int sl = ((CPB - 1 - (pfx + sp)) << 3) | batch;
        float mi = PM[(size_t)sl * QB + rowin];
        if (mi > mrun) {
            float sc = exp2f(mrun - mi);
            ls *= sc;
            os *= sc;
            mrun = mi;
        }
        float wgt = exp2f(mi - mrun);
        ls += PL[(size_t)sl * QB + rowin] * wgt;
        us4 po = *(const us4*)(PO + (size_t)sl * (QB * DIM) + rowin * DIM + d0);
        os[0] += bf2f(po[0]) * wgt;
        os[1] += bf2f(po[1]) * wgt;
        os[2] += bf2f(po[2]) * wgt;
        os[3] += bf2f(po[3]) * wgt;
    }
    const int grow = batch * SEQ + qi * 64 + rowin;
    float inv = 1.f / ls;
    f32x4 res = os * inv;
    *(f32x4*)(O + (size_t)grow * DIM + d0) = res;
}

extern "C" void kernel_launch(void* const* d_in, const int* in_sizes, int n_in,
                              void* d_out, int out_size, void* d_ws, size_t ws_size,
                              hipStream_t stream) {
    const float* Q = (const float*)d_in[0];
    const float* K = (const float*)d_in[1];
    const float* V = (const float*)d_in[2];
    float* O = (float*)d_out;
    (void)in_sizes; (void)n_in; (void)out_size; (void)ws_size;

    const size_t kvelems = (size_t)BATCH * SEQ * DIM;
    unsigned short* Kp = (unsigned short*)d_ws;
    unsigned short* Vp = Kp + kvelems;
    unsigned short* PO = Vp + kvelems;
    float* PM = (float*)(PO + (size_t)BATCH * CPB * QB * DIM);
    float* PL = PM + (size_t)BATCH * CPB * QB;

    prep_kernel<<<BATCH * NKT, 256, 0, stream>>>(K, V, Kp, Vp);
    fa_kernel<<<BATCH * CPB, 256, 0, stream>>>(Q, Kp, Vp, PO, PM, PL, O);
    combine_kernel<<<BATCH * 30 * 64 / 16, 256, 0, stream>>>(PO, PM, PL, O);
}

// Round 13
// 36.166 us; speedup vs baseline: 1.1382x; 1.1382x over previous
//
#include <hip/hip_runtime.h>
#include <hip/hip_bf16.h>

typedef __attribute__((ext_vector_type(8))) short bf16x8;
typedef __attribute__((ext_vector_type(4))) float f32x4;
typedef __attribute__((ext_vector_type(4))) unsigned short us4;

#define BATCH 8
#define SEQ 2048
#define DIM 64
#define QB 64                  // q rows per block (4 waves x 16)
#define NQT 32
#define NKT 32
#define TE 4096                // elems per 64x64 tile
#define CH 4                   // kv tiles per chunk
#define CPB 144                // chunks per batch = sum ceil((qi+1)/4)
#define QSCALE (0.125f * 1.44269504088896f)  // 1/sqrt(64) * log2(e)
#define THR 8.0f

__device__ __forceinline__ unsigned short f2bf(float f) {
    return __builtin_bit_cast(unsigned short, __float2bfloat16(f));
}
__device__ __forceinline__ float bf2f(unsigned short u) {
    return __builtin_bit_cast(float, (unsigned)u << 16);
}

__device__ __forceinline__ int kswz(int row, int d) {
    return (row * DIM + d) ^ ((row & 7) << 3);
}
__device__ __forceinline__ int vswz(int d, int kv) {
    return (d * 64 + kv) ^ ((((d & 7) ^ ((d >> 2) & 7)) & 7) << 3);
}
__device__ __forceinline__ int pswz(int row, int kv) {
    return (row * 64 + kv) ^ ((row & 7) << 3);
}

#define GLOAD16(gsrc, ldst)                                                     \
    __builtin_amdgcn_global_load_lds(                                           \
        (const __attribute__((address_space(1))) void*)(gsrc),                  \
        (__attribute__((address_space(3))) void*)(ldst), 16, 0, 0)

// ---- pre-pass: fp32 K,V -> bf16 swizzled tiles; blockIdx&7 = batch ----
__global__ __launch_bounds__(256) void prep_kernel(const float* __restrict__ K,
                                                   const float* __restrict__ V,
                                                   unsigned short* __restrict__ Kp,
                                                   unsigned short* __restrict__ Vp) {
    const int batch = blockIdx.x & 7;
    const int t = blockIdx.x >> 3;
    const int tile = batch * NKT + t;
    const int tid = threadIdx.x;
    const float* Kt = K + (size_t)tile * TE;
    const float* Vt = V + (size_t)tile * TE;
    unsigned short* Kd = Kp + (size_t)tile * TE;
    unsigned short* Vd = Vp + (size_t)tile * TE;
    #pragma unroll
    for (int i = 0; i < 4; ++i) {
        int idx = i * 256 + tid;
        int row = idx >> 4;
        int d0 = (idx & 15) << 2;
        f32x4 kf = *(const f32x4*)(Kt + row * DIM + d0);
        us4 kb = {f2bf(kf[0]), f2bf(kf[1]), f2bf(kf[2]), f2bf(kf[3])};
        *(us4*)(&Kd[kswz(row, d0)]) = kb;
    }
    const int dt4 = tid & 15, k4 = tid >> 4;
    f32x4 vf[4];
    #pragma unroll
    for (int rr = 0; rr < 4; ++rr)
        vf[rr] = *(const f32x4*)(Vt + (k4 * 4 + rr) * DIM + dt4 * 4);
    #pragma unroll
    for (int dd = 0; dd < 4; ++dd) {
        us4 vb = {f2bf(vf[0][dd]), f2bf(vf[1][dd]), f2bf(vf[2][dd]), f2bf(vf[3][dd])};
        *(us4*)(&Vd[vswz(dt4 * 4 + dd, k4 * 4)]) = vb;
    }
}

// ---- main flash kernel: block = (batch, q-tile, chunk of <=4 kv-tiles) ----
__global__ __launch_bounds__(256, 4) void fa_kernel(const float* __restrict__ Q,
                                                    const unsigned short* __restrict__ Kp,
                                                    const unsigned short* __restrict__ Vp,
                                                    unsigned short* __restrict__ PO,
                                                    float* __restrict__ PM,
                                                    float* __restrict__ PL,
                                                    float* __restrict__ O) {
    __shared__ unsigned short KL[2][4096];   // 16 KB
    __shared__ unsigned short VL[2][4096];   // 16 KB
    __shared__ unsigned short PB[4][1024];   // 8 KB  -> total 40960 B exactly

    const int tid = threadIdx.x;
    const int w = tid >> 6, lane = tid & 63, g = lane >> 4, c = lane & 15;

    // decode: chunk c0 within batch; big chunks (high qi) first
    const int slot = blockIdx.x;
    const int batch = slot & 7;
    const int c0 = (CPB - 1) - (slot >> 3);          // 0..143
    int g2 = 0;
    #pragma unroll
    for (int gg = 1; gg < 8; ++gg) g2 = (c0 >= 2 * gg * (gg + 1)) ? gg : g2;
    const int nc = g2 + 1;                           // chunks per q-tile in this group
    const int x = c0 - 2 * g2 * nc;
    const int qrow = (x >= nc) + (x >= 2 * nc) + (x >= 3 * nc);
    const int sp = x - qrow * nc;
    const int qi = 4 * g2 + qrow;

    const int q0 = qi * QB;
    const int nt = qi + 1;
    const int t0 = sp * CH;
    const int t1 = (t0 + CH < nt) ? (t0 + CH) : nt;
    const int tiles = t1 - t0;
    const bool dchunk = (t1 == nt);

    const unsigned short* Kb = Kp + (size_t)batch * NKT * TE;
    const unsigned short* Vb = Vp + (size_t)batch * NKT * TE;

#define STAGE_TILE(tidx, buf)                                          \
    do {                                                               \
        const char* Ks_ = (const char*)(Kb + (size_t)(tidx) * TE);     \
        const char* Vs_ = (const char*)(Vb + (size_t)(tidx) * TE);     \
        char* kd_ = (char*)&KL[buf][0];                                \
        char* vd_ = (char*)&VL[buf][0];                                \
        _Pragma("unroll")                                              \
        for (int i_ = 0; i_ < 2; ++i_) {                               \
            int off_ = (w * 2 + i_) * 1024;                            \
            GLOAD16(Ks_ + off_ + lane * 16, kd_ + off_);               \
            GLOAD16(Vs_ + off_ + lane * 16, vd_ + off_);               \
        }                                                              \
    } while (0)

    STAGE_TILE(t0, 0);

    // Q fragments (overlap with staging)
    const float* Qrow = Q + (size_t)(batch * SEQ + q0 + w * 16 + c) * DIM;
    f32x4 qf0 = *(const f32x4*)(Qrow + g * 8);
    f32x4 qf1 = *(const f32x4*)(Qrow + g * 8 + 4);
    f32x4 qf2 = *(const f32x4*)(Qrow + 32 + g * 8);
    f32x4 qf3 = *(const f32x4*)(Qrow + 32 + g * 8 + 4);
    bf16x8 qa[2];
    #pragma unroll
    for (int j = 0; j < 4; ++j) {
        qa[0][j]     = (short)f2bf(qf0[j] * QSCALE);
        qa[0][j + 4] = (short)f2bf(qf1[j] * QSCALE);
        qa[1][j]     = (short)f2bf(qf2[j] * QSCALE);
        qa[1][j + 4] = (short)f2bf(qf3[j] * QSCALE);
    }

    float m[4], lsum[4];
    f32x4 o[4];
    #pragma unroll
    for (int r = 0; r < 4; ++r) { m[r] = -1e30f; lsum[r] = 0.f; }
    #pragma unroll
    for (int dt = 0; dt < 4; ++dt) o[dt] = f32x4{0.f, 0.f, 0.f, 0.f};

    __builtin_amdgcn_sched_barrier(0);
    asm volatile("s_waitcnt vmcnt(0)" ::: "memory");
    __builtin_amdgcn_s_barrier();
    __builtin_amdgcn_sched_barrier(0);

    for (int u = 0; u < tiles; ++u) {
        const int cb = u & 1;
        const bool last = (u == tiles - 1);

        if (!last) STAGE_TILE(t0 + u + 1, cb ^ 1);

        // ---- QK^T ----
        f32x4 s[4];
        #pragma unroll
        for (int n = 0; n < 4; ++n) s[n] = f32x4{0.f, 0.f, 0.f, 0.f};
        __builtin_amdgcn_s_setprio(1);
        #pragma unroll
        for (int n = 0; n < 4; ++n)
            #pragma unroll
            for (int f = 0; f < 2; ++f) {
                bf16x8 kb = *(bf16x8*)(&KL[cb][kswz(n * 16 + c, f * 32 + g * 8)]);
                s[n] = __builtin_amdgcn_mfma_f32_16x16x32_bf16(qa[f], kb, s[n], 0, 0, 0);
            }
        __builtin_amdgcn_s_setprio(0);

        if (dchunk && last) {
            const int dbase = (nt - 1) * 64;
            #pragma unroll
            for (int n = 0; n < 4; ++n) {
                int col = dbase + n * 16 + c;
                #pragma unroll
                for (int r = 0; r < 4; ++r)
                    if (col > q0 + w * 16 + g * 4 + r) s[n][r] = -1e30f;
            }
        }

        // ---- softmax: local-max THR check (no cross-lane in common path) ----
        float pmx[4];
        #pragma unroll
        for (int r = 0; r < 4; ++r)
            pmx[r] = fmaxf(fmaxf(s[0][r], s[1][r]), fmaxf(s[2][r], s[3][r]));
        bool need = false;
        #pragma unroll
        for (int r = 0; r < 4; ++r) need |= (pmx[r] > m[r] + THR);
        if (__any(need)) {
            #pragma unroll
            for (int r = 0; r < 4; ++r) {
                float t2 = pmx[r];
                t2 = fmaxf(t2, __shfl_xor(t2, 1));
                t2 = fmaxf(t2, __shfl_xor(t2, 2));
                t2 = fmaxf(t2, __shfl_xor(t2, 4));
                t2 = fmaxf(t2, __shfl_xor(t2, 8));
                float mn = fmaxf(m[r], t2);
                float alpha = exp2f(m[r] - mn);
                m[r] = mn;
                lsum[r] *= alpha;
                #pragma unroll
                for (int dt = 0; dt < 4; ++dt) o[dt][r] *= alpha;
            }
        }
        #pragma unroll
        for (int n = 0; n < 4; ++n)
            #pragma unroll
            for (int r = 0; r < 4; ++r) {
                float pe = exp2f(s[n][r] - m[r]);
                s[n][r] = pe;
                lsum[r] += pe;          // per-lane partial; reduced in epilogue
            }

        // ---- P -> own wave LDS region (wave-local hazard, no barrier) ----
        unsigned short* Pw = &PB[w][0];
        #pragma unroll
        for (int n = 0; n < 4; ++n)
            #pragma unroll
            for (int r = 0; r < 4; ++r)
                Pw[pswz(g * 4 + r, n * 16 + c)] = f2bf(s[n][r]);
        asm volatile("s_waitcnt lgkmcnt(0)" ::: "memory");
        __builtin_amdgcn_sched_barrier(0);

        // ---- PV ----
        __builtin_amdgcn_s_setprio(1);
        #pragma unroll
        for (int ks = 0; ks < 2; ++ks) {
            bf16x8 pa = *(bf16x8*)(&Pw[pswz(c, ks * 32 + g * 8)]);
            #pragma unroll
            for (int dt = 0; dt < 4; ++dt) {
                bf16x8 vb = *(bf16x8*)(&VL[cb][vswz(dt * 16 + c, ks * 32 + g * 8)]);
                o[dt] = __builtin_amdgcn_mfma_f32_16x16x32_bf16(pa, vb, o[dt], 0, 0, 0);
            }
        }
        __builtin_amdgcn_s_setprio(0);

        if (!last) {
            __builtin_amdgcn_sched_barrier(0);
            asm volatile("s_waitcnt vmcnt(0)" ::: "memory");
            __builtin_amdgcn_s_barrier();
            __builtin_amdgcn_sched_barrier(0);
        }
    }

    // ---- reduce per-lane l partials across the 16-lane group ----
    float l[4];
    #pragma unroll
    for (int r = 0; r < 4; ++r) {
        float ts = lsum[r];
        ts += __shfl_xor(ts, 1);
        ts += __shfl_xor(ts, 2);
        ts += __shfl_xor(ts, 4);
        ts += __shfl_xor(ts, 8);
        l[r] = ts;
    }

    // ---- epilogue ----
    if (nt <= CH) {          // single chunk: direct O write
        #pragma unroll
        for (int r = 0; r < 4; ++r) {
            float inv = 1.f / l[r];
            float* Orow = O + (size_t)(batch * SEQ + q0 + w * 16 + g * 4 + r) * DIM;
            #pragma unroll
            for (int dt = 0; dt < 4; ++dt)
                Orow[dt * 16 + c] = o[dt][r] * inv;
        }
    } else {
        unsigned short* Pbase = PO + (size_t)slot * (QB * DIM);
        #pragma unroll
        for (int r = 0; r < 4; ++r) {
            int rowin = w * 16 + g * 4 + r;
            #pragma unroll
            for (int dt = 0; dt < 4; ++dt)
                Pbase[rowin * DIM + dt * 16 + c] = f2bf(o[dt][r]);
            if (c == 0) {
                PM[(size_t)slot * QB + rowin] = m[r];
                PL[(size_t)slot * QB + rowin] = l[r];
            }
        }
    }
#undef STAGE_TILE
}

// ---- combine (q-tiles with qi>=4), single-pass online, bf16 partials ----
__global__ __launch_bounds__(256) void combine_kernel(const unsigned short* __restrict__ PO,
                                                      const float* __restrict__ PM,
                                                      const float* __restrict__ PL,
                                                      float* __restrict__ O) {
    const int tid = threadIdx.x;
    const int ridx = blockIdx.x * 16 + (tid >> 4);
    const int d0 = (tid & 15) << 2;
    const int batch = ridx / 1792;          // 28 q-tiles x 64 rows per batch
    const int rem = ridx - batch * 1792;
    const int qi = 4 + (rem >> 6);
    const int rowin = rem & 63;
    const int a = qi >> 2, b = qi & 3;
    const int nc = a + 1;
    const int pfx = (a + 1) * (2 * a + b);

    float mrun = -1e30f, ls = 0.f;
    f32x4 os = {0.f, 0.f, 0.f, 0.f};
    for (int sp = 0; sp < nc; ++sp) {
        int sl = ((CPB - 1 - (pfx + sp)) << 3) | batch;
        float mi = PM[(size_t)sl * QB + rowin];
        if (mi > mrun) {
            float sc = exp2f(mrun - mi);
            ls *= sc;
            os *= sc;
            mrun = mi;
        }
        float wgt = exp2f(mi - mrun);
        ls += PL[(size_t)sl * QB + rowin] * wgt;
        us4 po = *(const us4*)(PO + (size_t)sl * (QB * DIM) + rowin * DIM + d0);
        os[0] += bf2f(po[0]) * wgt;
        os[1] += bf2f(po[1]) * wgt;
        os[2] += bf2f(po[2]) * wgt;
        os[3] += bf2f(po[3]) * wgt;
    }
    const int grow = batch * SEQ + qi * 64 + rowin;
    float inv = 1.f / ls;
    f32x4 res = os * inv;
    *(f32x4*)(O + (size_t)grow * DIM + d0) = res;
}

extern "C" void kernel_launch(void* const* d_in, const int* in_sizes, int n_in,
                              void* d_out, int out_size, void* d_ws, size_t ws_size,
                              hipStream_t stream) {
    const float* Q = (const float*)d_in[0];
    const float* K = (const float*)d_in[1];
    const float* V = (const float*)d_in[2];
    float* O = (float*)d_out;
    (void)in_sizes; (void)n_in; (void)out_size; (void)ws_size;

    const size_t kvelems = (size_t)BATCH * SEQ * DIM;
    unsigned short* Kp = (unsigned short*)d_ws;
    unsigned short* Vp = Kp + kvelems;
    unsigned short* PO = Vp + kvelems;
    float* PM = (float*)(PO + (size_t)BATCH * CPB * QB * DIM);
    float* PL = PM + (size_t)BATCH * CPB * QB;

    prep_kernel<<<BATCH * NKT, 256, 0, stream>>>(K, V, Kp, Vp);
    fa_kernel<<<BATCH * CPB, 256, 0, stream>>>(Q, Kp, Vp, PO, PM, PL, O);
    combine_kernel<<<BATCH * 28 * 64 / 16, 256, 0, stream>>>(PO, PM, PL, O);
}